// Round 1
// 130.869 us; speedup vs baseline: 1.0701x; 1.0701x over previous
//
#include <hip/hip_runtime.h>

#define N_BOND   100000
#define D_DIM    192
#define N_ETYPES 36
#define E_PER_TYPE 30000
#define BATCH    256
#define TOTAL_E  (N_ETYPES * E_PER_TYPE)
#define ACC_N    (N_ETYPES * BATCH)

// Kernel 1: hv[n] = dot(h[n, :], W).
// Quarter-wave (16 lanes) per row, 3x float4 per lane -> all 64 lanes load
// (previous version idled 16/64 lanes). First 36 blocks also zero acc, which
// removes the separate hipMemsetAsync dispatch from the timed graph.
__global__ void hv_kernel(const float* __restrict__ h, const float* __restrict__ W,
                          float* __restrict__ hv, float* __restrict__ acc) {
    int gid = blockIdx.x * blockDim.x + threadIdx.x;
    if (gid < ACC_N) acc[gid] = 0.f;   // acc zeroing folded in (runs before edge_kernel by stream order)

    int wave = gid >> 6;
    int lane = threadIdx.x & 63;
    int row  = wave * 4 + (lane >> 4); // 4 rows per wave
    int ql   = lane & 15;
    if (row >= N_BOND) return;

    const float4* hp = (const float4*)(h + (size_t)row * D_DIM);
    const float4* wp = (const float4*)W;
    float v = 0.f;
#pragma unroll
    for (int k = 0; k < 3; ++k) {
        float4 a = hp[ql + 16 * k];    // 16 lanes x 16B = 256B contiguous per step
        float4 w = wp[ql + 16 * k];    // 768B total, L1-resident
        v += a.x * w.x + a.y * w.y + a.z * w.z + a.w * w.w;
    }
    // reduce within the 16-lane quarter
#pragma unroll
    for (int d = 8; d > 0; d >>= 1) v += __shfl_down(v, d, 64);
    if (ql == 0) hv[row] = v;
}

// Kernel 2: segment-sum over edges, 4 edges per thread.
// key = t*BATCH + seg is globally non-decreasing (t grows with flat index, seg
// sorted within type, key jumps by >=1 at type boundaries). E_PER_TYPE % 4 == 0,
// so a thread's 4 edges never straddle an edge type.
// Step 1: serial segmented fold of the 4 edges inside the thread (segments
//         average ~117 consecutive edges, so intra-thread key changes are rare;
//         when they happen, flush the finished partial with one atomic).
// Step 2: 64-lane segmented inclusive scan over the trailing partials; last
//         lane of each key-run flushes. ~2 atomics per wave + ~9K boundary
//         atomics total over a 36KB acc.
__global__ void edge_kernel(const int* __restrict__ edge_src,
                            const int* __restrict__ edge_seg,
                            const float* __restrict__ hv,
                            float* __restrict__ acc) {
    int tid  = blockIdx.x * blockDim.x + threadIdx.x;
    int lane = threadIdx.x & 63;
    int e0   = tid * 4;
    bool valid = (e0 < TOTAL_E);
    int ec = valid ? e0 : (TOTAL_E - 4);      // clamp: invalid lanes join last segment with val=0
    int t  = ec / E_PER_TYPE;

    int4 s4 = ((const int4*)edge_seg)[ec >> 2];
    int4 r4 = ((const int4*)edge_src)[ec >> 2];
    float v0 = valid ? hv[r4.x] : 0.f;
    float v1 = valid ? hv[r4.y] : 0.f;
    float v2 = valid ? hv[r4.z] : 0.f;
    float v3 = valid ? hv[r4.w] : 0.f;

    int base = t * BATCH;
    int k0 = base + s4.x, k1 = base + s4.y, k2 = base + s4.z, k3 = base + s4.w;

    int   ck = k0;
    float cv = v0;
    if (k1 == ck) cv += v1; else { atomicAdd(&acc[ck], cv); ck = k1; cv = v1; }
    if (k2 == ck) cv += v2; else { atomicAdd(&acc[ck], cv); ck = k2; cv = v2; }
    if (k3 == ck) cv += v3; else { atomicAdd(&acc[ck], cv); ck = k3; cv = v3; }

    // segmented inclusive scan over trailing partials (keys sorted across lanes)
#pragma unroll
    for (int d = 1; d < 64; d <<= 1) {
        float uv = __shfl_up(cv, d, 64);
        int   uk = __shfl_up(ck, d, 64);
        if (lane >= d && uk == ck) cv += uv;
    }
    int nk = __shfl_down(ck, 1, 64);
    if (lane == 63 || nk != ck) atomicAdd(&acc[ck], cv);
}

// Kernel 3: mask + softmax over the 36 types for each of 256 graphs.
// Thread b handles graph b; acc reads are coalesced (acc[t*BATCH + b]).
__global__ void softmax_kernel(const float* __restrict__ acc,
                               const void* __restrict__ mask,
                               float* __restrict__ out) {
    int b = threadIdx.x;  // 256 threads, 1 block

    // Detect mask storage width: bool(1B) vs int32(4B). For int32 storage every
    // word is exactly 0 or 1; for packed 0/1 bytes a word >1 appears with
    // overwhelming probability within 16 words.
    const unsigned int* mi = (const unsigned int*)mask;
    bool is_u8 = false;
#pragma unroll
    for (int i = 0; i < 16; ++i) is_u8 |= (mi[i] > 1u);
    const unsigned char* m8  = (const unsigned char*)mask;
    const int*           m32 = (const int*)mask;

    float v[N_ETYPES];
    float mx = -1e30f;
#pragma unroll
    for (int t = 0; t < N_ETYPES; ++t) {
        float x = acc[t * BATCH + b];
        bool masked = is_u8 ? (m8[b * N_ETYPES + t] != 0)
                            : (m32[b * N_ETYPES + t] != 0);
        x = masked ? -1e9f : x;
        v[t] = x;
        mx = fmaxf(mx, x);
    }
    float s = 0.f;
#pragma unroll
    for (int t = 0; t < N_ETYPES; ++t) { v[t] = expf(v[t] - mx); s += v[t]; }
    float inv = 1.f / s;
#pragma unroll
    for (int t = 0; t < N_ETYPES; ++t) out[b * N_ETYPES + t] = v[t] * inv;
}

extern "C" void kernel_launch(void* const* d_in, const int* in_sizes, int n_in,
                              void* d_out, int out_size, void* d_ws, size_t ws_size,
                              hipStream_t stream) {
    const float* h        = (const float*)d_in[0];   // [100000, 192]
    const float* W        = (const float*)d_in[1];   // [192, 1]
    const int*   edge_src = (const int*)d_in[2];     // [36, 30000]
    const int*   edge_seg = (const int*)d_in[3];     // [36, 30000]
    const void*  mask     = d_in[4];                 // [256, 36] bool (width auto-detected)
    float*       out      = (float*)d_out;           // [256, 36]

    float* hv  = (float*)d_ws;                       // 100000 floats
    float* acc = (float*)((char*)d_ws + 400128);     // 9216 floats, 128B-aligned

    // 100000 rows, 4 rows/wave, 4 waves/block -> 16 rows per 256-thread block
    hipLaunchKernelGGL(hv_kernel, dim3(N_BOND / 16), dim3(256), 0, stream, h, W, hv, acc);

    // 4 edges per thread
    int eb = (TOTAL_E / 4 + 255) / 256;
    hipLaunchKernelGGL(edge_kernel, dim3(eb), dim3(256), 0, stream, edge_src, edge_seg, hv, acc);

    hipLaunchKernelGGL(softmax_kernel, dim3(1), dim3(256), 0, stream, acc, mask, out);
}